// Round 1
// baseline (555.730 us; speedup 1.0000x reference)
//
#include <hip/hip_runtime.h>
#include <hip/hip_bf16.h>
#include <math.h>

typedef unsigned short ushort_t;
typedef unsigned int uint_t;

typedef __attribute__((ext_vector_type(8))) __bf16 bf16x8;
typedef __attribute__((ext_vector_type(4))) float f32x4;

#define BATCH 32768
#define FDIM  845
#define FP    896     // padded (multiple of 128)
#define BM    64
#define BN    128
#define BK    32
#define KT    27      // ceil(845/32)
#define NTI   7       // 896/128

__device__ __forceinline__ int fld(int n) {
    return (n < 13) ? n : (((n - 13) >> 5) + 13);
}

__device__ __forceinline__ ushort_t f2bf(float f) {
    uint_t u = __builtin_bit_cast(uint_t, f);
    uint_t r = u + 0x7FFFu + ((u >> 16) & 1u);   // RNE
    return (ushort_t)(r >> 16);
}

// Build WbT[n][k] = bf16( a[k,n] * dot(V_k, V_n) ), n,k < 845
// plus the linear column: WbT[845][k] = w_lin[k]; all pads = 0.
__global__ void prep_w(const float* __restrict__ fm,
                       const float* __restrict__ a,
                       const float* __restrict__ wl,
                       ushort_t* __restrict__ WbT) {
    int t = blockIdx.x * 256 + threadIdx.x;   // t in [0, 896*896)
    int i = t % FP;        // k index (contracted with X)
    int j = t / FP;        // n index (output column)
    float w = 0.0f;
    if (i < FDIM && j < FDIM) {
        const float* Vi = fm + (size_t)(i * 39 + fld(i)) * 32;
        const float* Vj = fm + (size_t)(j * 39 + fld(j)) * 32;
        float d = 0.0f;
        #pragma unroll
        for (int k = 0; k < 32; ++k) d += Vi[k] * Vj[k];
        w = a[(size_t)i * FDIM + j] * d;
    } else if (j == FDIM && i < FDIM) {
        w = wl[i];   // linear term folded in as column 845
    }
    WbT[(size_t)j * FP + i] = f2bf(w);
}

// quad[b] = sum_n (sum_k Xb[b,k] W[k,n]) * xfac[b,n],  xfac = X (n<845), 1 (n==845), 0 else
// out[b] = sigmoid(quad[b] + b_lin)
__global__ __launch_bounds__(256, 2)
void ffm_main(const float* __restrict__ X,
              const ushort_t* __restrict__ WbT,
              const float* __restrict__ blin,
              float* __restrict__ out) {
    __shared__ ushort_t Xs[BM * 40];     // row r at r*40 (pad 32->40 vs bank conflicts)
    __shared__ ushort_t Ws[BN * 40];     // row n at n*40

    const int tid  = threadIdx.x;
    const int wave = tid >> 6;
    const int lane = tid & 63;
    const int l15  = lane & 15;
    const int l4   = lane >> 4;
    const int row0 = blockIdx.x * BM;

    float qp[4] = {0.f, 0.f, 0.f, 0.f};

    for (int nb = 0; nb < NTI; ++nb) {
        const int n0 = nb * BN;
        f32x4 acc[8];
        #pragma unroll
        for (int nt = 0; nt < 8; ++nt) acc[nt] = (f32x4){0.f, 0.f, 0.f, 0.f};

        for (int kt = 0; kt < KT; ++kt) {
            const int k0 = kt * BK;
            __syncthreads();   // protect LDS from previous iter's readers

            // ---- stage X tile (64 x 32) fp32 -> bf16 ----
            {
                const int r   = tid >> 2;
                const int seg = tid & 3;
                const int kb  = k0 + seg * 8;
                const float* xp = X + (size_t)(row0 + r) * FDIM + kb;
                union { ushort_t u[8]; uint4 v; } pk;
                #pragma unroll
                for (int j = 0; j < 8; ++j) {
                    float v = (kb + j < FDIM) ? xp[j] : 0.0f;
                    pk.u[j] = f2bf(v);
                }
                *(uint4*)&Xs[r * 40 + seg * 8] = pk.v;
            }
            // ---- stage W tile (128 x 32) bf16 copy, transposed layout ----
            #pragma unroll
            for (int s = tid; s < 512; s += 256) {
                const int n   = s >> 2;
                const int seg = s & 3;
                uint4 v = *(const uint4*)&WbT[(size_t)(n0 + n) * FP + k0 + seg * 8];
                *(uint4*)&Ws[n * 40 + seg * 8] = v;
            }
            __syncthreads();

            // ---- MFMA: wave owns rows [wave*16, wave*16+16) x all 128 cols ----
            bf16x8 af = *(const bf16x8*)&Xs[(wave * 16 + l15) * 40 + l4 * 8];
            #pragma unroll
            for (int nt = 0; nt < 8; ++nt) {
                bf16x8 bf = *(const bf16x8*)&Ws[(nt * 16 + l15) * 40 + l4 * 8];
                acc[nt] = __builtin_amdgcn_mfma_f32_16x16x32_bf16(af, bf, acc[nt], 0, 0, 0);
            }
        }

        // ---- fold this n-tile into quad partials ----
        #pragma unroll
        for (int nt = 0; nt < 8; ++nt) {
            const int col = n0 + nt * 16 + l15;
            #pragma unroll
            for (int r = 0; r < 4; ++r) {
                const int row = row0 + wave * 16 + l4 * 4 + r;
                float xf = (col < FDIM) ? X[(size_t)row * FDIM + col]
                                        : (col == FDIM ? 1.0f : 0.0f);
                qp[r] += acc[nt][r] * xf;
            }
        }
    }

    // reduce across the 16 column-lanes (bits 0..3 of lane id)
    #pragma unroll
    for (int off = 1; off < 16; off <<= 1) {
        #pragma unroll
        for (int r = 0; r < 4; ++r) qp[r] += __shfl_xor(qp[r], off, 64);
    }

    if (l15 == 0) {
        const float bl = blin[0];
        #pragma unroll
        for (int r = 0; r < 4; ++r) {
            float z = qp[r] + bl;
            out[row0 + wave * 16 + l4 * 4 + r] = 1.0f / (1.0f + expf(-z));
        }
    }
}

extern "C" void kernel_launch(void* const* d_in, const int* in_sizes, int n_in,
                              void* d_out, int out_size, void* d_ws, size_t ws_size,
                              hipStream_t stream) {
    const float* X  = (const float*)d_in[0];   // [32768, 845]
    const float* fm = (const float*)d_in[1];   // [845, 39, 32]
    const float* a  = (const float*)d_in[2];   // [845, 845]
    const float* wl = (const float*)d_in[3];   // [845, 1]
    const float* bl = (const float*)d_in[4];   // [1]
    float* out = (float*)d_out;                // [32768]

    ushort_t* WbT = (ushort_t*)d_ws;           // 896*896*2 = 1.6 MB

    prep_w<<<(FP * FP) / 256, 256, 0, stream>>>(fm, a, wl, WbT);
    ffm_main<<<BATCH / BM, 256, 0, stream>>>(X, WbT, bl, out);
}

// Round 2
// 311.810 us; speedup vs baseline: 1.7823x; 1.7823x over previous
//
#include <hip/hip_runtime.h>
#include <hip/hip_bf16.h>
#include <math.h>

typedef unsigned short ushort_t;
typedef unsigned int   uint_t;

typedef __attribute__((ext_vector_type(8))) __bf16 bf16x8;
typedef __attribute__((ext_vector_type(4))) float  f32x4;

#define BATCH 32768
#define FDIM  845
#define FP    896      // padded feature dim (7*128)
#define KT    27       // 27*32 = 864 >= 846 contracted cols
#define NBLK  7        // 896/128 n-tiles
#define MBLK  256      // 32768/128 m-tiles

__device__ __forceinline__ int fld(int n) { return (n < 13) ? n : (((n - 13) >> 5) + 13); }

__device__ __forceinline__ ushort_t f2bf(float f) {
    uint_t u = __builtin_bit_cast(uint_t, f);
    uint_t r = u + 0x7FFFu + ((u >> 16) & 1u);   // RNE
    return (ushort_t)(r >> 16);
}
__device__ __forceinline__ float bf2f(ushort_t h) {
    uint_t u = ((uint_t)h) << 16;
    return __builtin_bit_cast(float, u);
}

__device__ __forceinline__ void gload_lds16(const ushort_t* g, ushort_t* l) {
    __builtin_amdgcn_global_load_lds(
        (const __attribute__((address_space(1))) void*)g,
        (__attribute__((address_space(3))) void*)l, 16, 0, 0);
}

// ---- pass 0: X fp32 -> Xb bf16 [32768 x 896]; col 845 = 1.0 (linear x-factor), cols>845 = 0
__global__ void conv_x(const float* __restrict__ X, ushort_t* __restrict__ Xb) {
    uint_t p   = blockIdx.x * 256 + threadIdx.x;   // [0, 32768*448)
    uint_t row = p / 448;
    uint_t c0  = (p % 448) * 2;
    ushort_t v[2];
    #pragma unroll
    for (int j = 0; j < 2; ++j) {
        uint_t c = c0 + j;
        float f = (c < FDIM) ? X[(size_t)row * FDIM + c] : (c == FDIM ? 1.0f : 0.0f);
        v[j] = f2bf(f);
    }
    *(ushort2*)&Xb[(size_t)row * FP + c0] = make_ushort2(v[0], v[1]);
}

// ---- pass 1: gather own-field vectors V[896 x 32] fp32 (rows >= 845 zeroed)
__global__ void gather_v(const float* __restrict__ fm, float* __restrict__ V) {
    int idx = blockIdx.x * 256 + threadIdx.x;   // [0, 896*32)
    int row = idx >> 5, k = idx & 31;
    V[idx] = (row < FDIM) ? fm[(size_t)(row * 39 + fld(row)) * 32 + k] : 0.0f;
}

// ---- pass 2: WbT[n][k] = bf16(a[k,n] * <V_k, V_n>); WbT[845][k<845] = w_lin[k]; pads 0
__global__ void prep_w(const float* __restrict__ a, const float* __restrict__ wl,
                       const float* __restrict__ V, ushort_t* __restrict__ WbT) {
    const int bx = blockIdx.x;               // 14*14 blocks of 64x64
    const int i0 = (bx % 14) * 64, j0 = (bx / 14) * 64;
    const int ti = (threadIdx.x >> 4) * 4;   // 4x4 entries per thread
    const int tj = (threadIdx.x & 15) * 4;
    float d[4][4] = {};
    const float4* Vi = (const float4*)(V + (size_t)(i0 + ti) * 32);
    const float4* Vj = (const float4*)(V + (size_t)(j0 + tj) * 32);
    #pragma unroll
    for (int kc = 0; kc < 8; ++kc) {
        float4 vi[4], vj[4];
        #pragma unroll
        for (int q = 0; q < 4; ++q) { vi[q] = Vi[q * 8 + kc]; vj[q] = Vj[q * 8 + kc]; }
        #pragma unroll
        for (int q = 0; q < 4; ++q)
            #pragma unroll
            for (int r = 0; r < 4; ++r)
                d[q][r] += vi[q].x * vj[r].x + vi[q].y * vj[r].y +
                           vi[q].z * vj[r].z + vi[q].w * vj[r].w;
    }
    #pragma unroll
    for (int q = 0; q < 4; ++q)
        #pragma unroll
        for (int r = 0; r < 4; ++r) {
            int i = i0 + ti + q, j = j0 + tj + r;
            float w = 0.0f;
            if (i < FDIM && j < FDIM)      w = a[(size_t)i * FDIM + j] * d[q][r];
            else if (j == FDIM && i < FDIM) w = wl[i];
            WbT[(size_t)j * FP + i] = f2bf(w);
        }
}

// ---- pass 3: m97-style 128x128x32 GEMM, fused quad epilogue
__global__ __launch_bounds__(256, 2)
void ffm_gemm(const ushort_t* __restrict__ Xb, const ushort_t* __restrict__ WbT,
              float* __restrict__ qpart) {
    __shared__ ushort_t As[128 * 32];   // row-major, 32 bf16 per row (global_load_lds layout)
    __shared__ ushort_t Bs[128 * 32];

    const int tid  = threadIdx.x;
    const int wave = tid >> 6, lane = tid & 63;
    const int l15  = lane & 15, l4 = lane >> 4;
    const int wm   = wave >> 1, wn = wave & 1;
    const int nb   = blockIdx.x % NBLK;
    const int m0   = (blockIdx.x / NBLK) * 128;
    const int n0   = nb * 128;

    const int srow  = lane >> 2;   // staging: 16 rows x 4 slots per wave-instr
    const int kslot = lane & 3;

    f32x4 acc[4][4];
    #pragma unroll
    for (int i = 0; i < 4; ++i)
        #pragma unroll
        for (int j = 0; j < 4; ++j) acc[i][j] = (f32x4){0.f, 0.f, 0.f, 0.f};

    for (int kt = 0; kt < KT; ++kt) {
        const int k0 = kt * 32;
        __syncthreads();
        #pragma unroll
        for (int half = 0; half < 2; ++half) {
            const int row = wave * 32 + half * 16 + srow;          // tile-local row
            const int ksg = kslot ^ ((row >> 1) & 3);              // XOR bank swizzle
            gload_lds16(Xb  + (size_t)(m0 + row) * FP + k0 + ksg * 8,
                        &As[(wave * 32 + half * 16) * 32]);
            gload_lds16(WbT + (size_t)(n0 + row) * FP + k0 + ksg * 8,
                        &Bs[(wave * 32 + half * 16) * 32]);
        }
        __syncthreads();

        bf16x8 af[4], bfv[4];
        #pragma unroll
        for (int i = 0; i < 4; ++i) {
            const int r = wm * 64 + i * 16 + l15;
            const int s = l4 ^ ((r >> 1) & 3);
            af[i] = *(const bf16x8*)&As[r * 32 + s * 8];
        }
        #pragma unroll
        for (int j = 0; j < 4; ++j) {
            const int r = wn * 64 + j * 16 + l15;
            const int s = l4 ^ ((r >> 1) & 3);
            bfv[j] = *(const bf16x8*)&Bs[r * 32 + s * 8];
        }
        #pragma unroll
        for (int i = 0; i < 4; ++i)
            #pragma unroll
            for (int j = 0; j < 4; ++j)
                acc[i][j] = __builtin_amdgcn_mfma_f32_16x16x32_bf16(af[i], bfv[j], acc[i][j], 0, 0, 0);
    }

    // fused epilogue: quad partial = sum_cols acc * Xb[row][col]
    float q[4][4] = {};   // [i][reg]
    #pragma unroll
    for (int i = 0; i < 4; ++i)
        #pragma unroll
        for (int j = 0; j < 4; ++j) {
            const int col = n0 + wn * 64 + j * 16 + l15;
            #pragma unroll
            for (int r = 0; r < 4; ++r) {
                const int row = m0 + wm * 64 + i * 16 + l4 * 4 + r;
                q[i][r] += acc[i][j][r] * bf2f(Xb[(size_t)row * FP + col]);
            }
        }
    #pragma unroll
    for (int off = 1; off < 16; off <<= 1)
        #pragma unroll
        for (int i = 0; i < 4; ++i)
            #pragma unroll
            for (int r = 0; r < 4; ++r) q[i][r] += __shfl_xor(q[i][r], off, 64);

    if (l15 == 0) {
        float* dst = qpart + (size_t)(nb * 2 + wn) * BATCH;
        #pragma unroll
        for (int i = 0; i < 4; ++i)
            #pragma unroll
            for (int r = 0; r < 4; ++r)
                dst[m0 + wm * 64 + i * 16 + l4 * 4 + r] = q[i][r];
    }
}

// ---- pass 4: sum 14 partials + bias, sigmoid
__global__ void finish(const float* __restrict__ qpart, const float* __restrict__ blin,
                       float* __restrict__ out) {
    int b = blockIdx.x * 256 + threadIdx.x;
    float s = blin[0];
    #pragma unroll
    for (int p = 0; p < 14; ++p) s += qpart[(size_t)p * BATCH + b];
    out[b] = 1.0f / (1.0f + expf(-s));
}

extern "C" void kernel_launch(void* const* d_in, const int* in_sizes, int n_in,
                              void* d_out, int out_size, void* d_ws, size_t ws_size,
                              hipStream_t stream) {
    const float* X  = (const float*)d_in[0];   // [32768, 845]
    const float* fm = (const float*)d_in[1];   // [845, 39, 32]
    const float* a  = (const float*)d_in[2];   // [845, 845]
    const float* wl = (const float*)d_in[3];   // [845, 1]
    const float* bl = (const float*)d_in[4];   // [1]
    float* out = (float*)d_out;                // [32768]

    char* ws = (char*)d_ws;
    ushort_t* Xb    = (ushort_t*)ws;                          // 58,720,256 B
    ushort_t* WbT   = (ushort_t*)(ws + 58720256);             //  1,605,632 B
    float*    V     = (float*)   (ws + 60325888);             //    114,688 B
    float*    qpart = (float*)   (ws + 60440576);             //  1,835,008 B (14 slices)

    conv_x  <<<(BATCH * 448) / 256, 256, 0, stream>>>(X, Xb);
    gather_v<<<(FP * 32) / 256,     256, 0, stream>>>(fm, V);
    prep_w  <<<14 * 14,             256, 0, stream>>>(a, wl, V, WbT);
    ffm_gemm<<<MBLK * NBLK,         256, 0, stream>>>(Xb, WbT, qpart);
    finish  <<<BATCH / 256,         256, 0, stream>>>(qpart, bl, out);
}

// Round 3
// 250.560 us; speedup vs baseline: 2.2180x; 1.2445x over previous
//
#include <hip/hip_runtime.h>
#include <hip/hip_bf16.h>
#include <math.h>

typedef unsigned short ushort_t;
typedef unsigned int   uint_t;

typedef __attribute__((ext_vector_type(8))) __bf16 bf16x8;
typedef __attribute__((ext_vector_type(4))) float  f32x4;

#define BATCH 32768
#define FDIM  845
#define FP    896      // padded feature dim (7*128)
#define KT    27       // 27*32 = 864 >= 846 contracted cols
#define NBLK  7        // 896/128 n-tiles
#define MBLK  256      // 32768/128 m-tiles

__device__ __forceinline__ int fld(int n) { return (n < 13) ? n : (((n - 13) >> 5) + 13); }

__device__ __forceinline__ ushort_t f2bf(float f) {
    uint_t u = __builtin_bit_cast(uint_t, f);
    uint_t r = u + 0x7FFFu + ((u >> 16) & 1u);   // RNE
    return (ushort_t)(r >> 16);
}
__device__ __forceinline__ float bf2f(ushort_t h) {
    uint_t u = ((uint_t)h) << 16;
    return __builtin_bit_cast(float, u);
}

__device__ __forceinline__ void gload_lds16(const ushort_t* g, ushort_t* l) {
    __builtin_amdgcn_global_load_lds(
        (const __attribute__((address_space(1))) void*)g,
        (__attribute__((address_space(3))) void*)l, 16, 0, 0);
}

// ---- pass 0: X fp32 -> Xb bf16 [32768 x 896]; col 845 = 1.0 (linear x-factor), cols>845 = 0
__global__ void conv_x(const float* __restrict__ X, ushort_t* __restrict__ Xb) {
    uint_t p   = blockIdx.x * 256 + threadIdx.x;   // [0, 32768*448)
    uint_t row = p / 448;
    uint_t c0  = (p % 448) * 2;
    ushort_t v[2];
    #pragma unroll
    for (int j = 0; j < 2; ++j) {
        uint_t c = c0 + j;
        float f = (c < FDIM) ? X[(size_t)row * FDIM + c] : (c == FDIM ? 1.0f : 0.0f);
        v[j] = f2bf(f);
    }
    *(ushort2*)&Xb[(size_t)row * FP + c0] = make_ushort2(v[0], v[1]);
}

// ---- pass 1: gather own-field vectors, bf16: Vb[896 x 32] (rows >= 845 zeroed)
__global__ void gather_v(const float* __restrict__ fm, ushort_t* __restrict__ Vb) {
    int idx = blockIdx.x * 256 + threadIdx.x;   // [0, 896*32)
    int row = idx >> 5, k = idx & 31;
    float v = (row < FDIM) ? fm[(size_t)(row * 39 + fld(row)) * 32 + k] : 0.0f;
    Vb[idx] = f2bf(v);
}

// ---- pass 2: WbT[j][i] = bf16(a[i,j] * <V_i, V_j>) via MFMA; WbT[845][i<845] = w_lin[i]
// 196 blocks, one 64x64 (i x j) output tile each. a-tile staged coalesced into LDS,
// read transposed (pad 65 -> conflict-free). P = V V^T: one 16x16x32 MFMA per subtile.
__global__ __launch_bounds__(256, 2)
void prep_w(const float* __restrict__ a, const float* __restrict__ wl,
            const ushort_t* __restrict__ Vb, ushort_t* __restrict__ WbT) {
    __shared__ float As[64 * 65];
    const int bx = blockIdx.x;
    const int i0 = (bx % 14) * 64, j0 = (bx / 14) * 64;
    const int tid  = threadIdx.x;
    const int wave = tid >> 6, lane = tid & 63;
    const int l15  = lane & 15, l4 = lane >> 4;

    // stage a[i][j] tile, coalesced along j
    {
        const int row = tid >> 2, seg = tid & 3;
        const int gi  = i0 + row;
        #pragma unroll
        for (int q = 0; q < 16; ++q) {
            const int jl = seg * 16 + q, gj = j0 + jl;
            float v = (gi < FDIM && gj < FDIM) ? a[(size_t)gi * FDIM + gj] : 0.0f;
            As[row * 65 + jl] = v;
        }
    }

    // P tiles: wave owns 16 j-rows x 64 i-cols. A-frag = V rows j, B-frag = V rows i.
    bf16x8 af = *(const bf16x8*)&Vb[(size_t)(j0 + wave * 16 + l15) * 32 + l4 * 8];
    f32x4 acc[4];
    #pragma unroll
    for (int it = 0; it < 4; ++it) {
        bf16x8 bf = *(const bf16x8*)&Vb[(size_t)(i0 + it * 16 + l15) * 32 + l4 * 8];
        acc[it] = __builtin_amdgcn_mfma_f32_16x16x32_bf16(af, bf, (f32x4){0.f,0.f,0.f,0.f}, 0, 0, 0);
    }
    __syncthreads();

    // epilogue: w = a[i][j] * P[j][i]; store WbT[j][i] (i contiguous across l15)
    #pragma unroll
    for (int it = 0; it < 4; ++it) {
        #pragma unroll
        for (int r = 0; r < 4; ++r) {
            const int jl = wave * 16 + l4 * 4 + r;   // C-layout row = m = j
            const int il = it * 16 + l15;            // C-layout col = n = i
            const int gi = i0 + il, gj = j0 + jl;
            float w = acc[it][r] * As[il * 65 + jl];
            if (gj == FDIM) w = (gi < FDIM) ? wl[gi] : 0.0f;
            WbT[(size_t)gj * FP + gi] = f2bf(w);
        }
    }
}

// ---- pass 3: m97-style 128x128x32 GEMM, fused quad epilogue, XCD-aware swizzle
__global__ __launch_bounds__(256, 2)
void ffm_gemm(const ushort_t* __restrict__ Xb, const ushort_t* __restrict__ WbT,
              float* __restrict__ qpart) {
    __shared__ ushort_t As[128 * 32];   // row-major, 32 bf16 per row (global_load_lds layout)
    __shared__ ushort_t Bs[128 * 32];

    const int tid  = threadIdx.x;
    const int wave = tid >> 6, lane = tid & 63;
    const int l15  = lane & 15, l4 = lane >> 4;
    const int wm   = wave >> 1, wn = wave & 1;

    // XCD-aware swizzle: blocks sharing an m-strip stay on one XCD (bid % 8 heuristic)
    const int bid  = blockIdx.x;
    const int xcd  = bid & 7;
    const int slot = bid >> 3;            // 0..223
    const int nb   = slot % 7;
    const int m0   = (xcd * 32 + slot / 7) * 128;
    const int n0   = nb * 128;

    const int srow  = lane >> 2;   // staging: 16 rows x 4 slots per wave-instr
    const int kslot = lane & 3;

    f32x4 acc[4][4];
    #pragma unroll
    for (int i = 0; i < 4; ++i)
        #pragma unroll
        for (int j = 0; j < 4; ++j) acc[i][j] = (f32x4){0.f, 0.f, 0.f, 0.f};

    for (int kt = 0; kt < KT; ++kt) {
        const int k0 = kt * 32;
        __syncthreads();
        #pragma unroll
        for (int half = 0; half < 2; ++half) {
            const int row = wave * 32 + half * 16 + srow;          // tile-local row
            const int ksg = kslot ^ ((row >> 1) & 3);              // XOR bank swizzle
            gload_lds16(Xb  + (size_t)(m0 + row) * FP + k0 + ksg * 8,
                        &As[(wave * 32 + half * 16) * 32]);
            gload_lds16(WbT + (size_t)(n0 + row) * FP + k0 + ksg * 8,
                        &Bs[(wave * 32 + half * 16) * 32]);
        }
        __syncthreads();

        bf16x8 af[4], bfv[4];
        #pragma unroll
        for (int i = 0; i < 4; ++i) {
            const int r = wm * 64 + i * 16 + l15;
            const int s = l4 ^ ((r >> 1) & 3);
            af[i] = *(const bf16x8*)&As[r * 32 + s * 8];
        }
        #pragma unroll
        for (int j = 0; j < 4; ++j) {
            const int r = wn * 64 + j * 16 + l15;
            const int s = l4 ^ ((r >> 1) & 3);
            bfv[j] = *(const bf16x8*)&Bs[r * 32 + s * 8];
        }
        #pragma unroll
        for (int i = 0; i < 4; ++i)
            #pragma unroll
            for (int j = 0; j < 4; ++j)
                acc[i][j] = __builtin_amdgcn_mfma_f32_16x16x32_bf16(af[i], bfv[j], acc[i][j], 0, 0, 0);
    }

    // fused epilogue: quad partial = sum_cols acc * Xb[row][col]
    float q[4][4] = {};   // [i][reg]
    #pragma unroll
    for (int i = 0; i < 4; ++i)
        #pragma unroll
        for (int j = 0; j < 4; ++j) {
            const int col = n0 + wn * 64 + j * 16 + l15;
            #pragma unroll
            for (int r = 0; r < 4; ++r) {
                const int row = m0 + wm * 64 + i * 16 + l4 * 4 + r;
                q[i][r] += acc[i][j][r] * bf2f(Xb[(size_t)row * FP + col]);
            }
        }
    #pragma unroll
    for (int off = 1; off < 16; off <<= 1)
        #pragma unroll
        for (int i = 0; i < 4; ++i)
            #pragma unroll
            for (int r = 0; r < 4; ++r) q[i][r] += __shfl_xor(q[i][r], off, 64);

    if (l15 == 0) {
        float* dst = qpart + (size_t)(nb * 2 + wn) * BATCH;
        #pragma unroll
        for (int i = 0; i < 4; ++i)
            #pragma unroll
            for (int r = 0; r < 4; ++r)
                dst[m0 + wm * 64 + i * 16 + l4 * 4 + r] = q[i][r];
    }
}

// ---- pass 4: sum 14 partials + bias, sigmoid
__global__ void finish(const float* __restrict__ qpart, const float* __restrict__ blin,
                       float* __restrict__ out) {
    int b = blockIdx.x * 256 + threadIdx.x;
    float s = blin[0];
    #pragma unroll
    for (int p = 0; p < 14; ++p) s += qpart[(size_t)p * BATCH + b];
    out[b] = 1.0f / (1.0f + expf(-s));
}

extern "C" void kernel_launch(void* const* d_in, const int* in_sizes, int n_in,
                              void* d_out, int out_size, void* d_ws, size_t ws_size,
                              hipStream_t stream) {
    const float* X  = (const float*)d_in[0];   // [32768, 845]
    const float* fm = (const float*)d_in[1];   // [845, 39, 32]
    const float* a  = (const float*)d_in[2];   // [845, 845]
    const float* wl = (const float*)d_in[3];   // [845, 1]
    const float* bl = (const float*)d_in[4];   // [1]
    float* out = (float*)d_out;                // [32768]

    char* ws = (char*)d_ws;
    ushort_t* Xb    = (ushort_t*)ws;                          // 58,720,256 B
    ushort_t* WbT   = (ushort_t*)(ws + 58720256);             //  1,605,632 B
    ushort_t* Vb    = (ushort_t*)(ws + 60325888);             //     57,344 B
    float*    qpart = (float*)   (ws + 60383232);             //  1,835,008 B (14 slices)

    conv_x  <<<(BATCH * 448) / 256, 256, 0, stream>>>(X, Xb);
    gather_v<<<(FP * 32) / 256,     256, 0, stream>>>(fm, Vb);
    prep_w  <<<14 * 14,             256, 0, stream>>>(a, wl, Vb, WbT);
    ffm_gemm<<<MBLK * NBLK,         256, 0, stream>>>(Xb, WbT, qpart);
    finish  <<<BATCH / 256,         256, 0, stream>>>(qpart, bl, out);
}